// Round 5
// baseline (324.581 us; speedup 1.0000x reference)
//
#include <hip/hip_runtime.h>

// NCC loss (win=21) on vol [B=2, C=1, X=160, Y=192, Z=160] fp32.
// K1: products + z-filter (register sliding window), mirrors boundary rows to S.
// K2: y-filter in place, per-channel float4 streams, 11-deep REGISTER delay line
//     (write row y-11 at step y), leaving value re-read from global. No LDS.
// K3: x-filter + cc + reduce. K4: finalize.

#define B_   2
#define X_   160
#define Y_   192
#define Z_   160
#define WIN_ 21
#define HALF 10
#define YZ   (Y_ * Z_)                       // 30720
#define NTOT ((size_t)B_ * X_ * Y_ * Z_)     // 9830400
#define XSEG 40                              // K3: 4 x-segments
#define RZ   8                               // K1 outputs per thread
#define CHUNKS (Z_ / RZ)                     // 20
#define SXN  (B_ * X_)                       // 320 (b*X + x)
#define SROWS 42                             // S: 2 boundaries x 21 rows: [53,73],[117,137]

// vector-or-zero load (float4 always fully in- or out-of-bounds; Z_ % 4 == 0)
__device__ __forceinline__ float4 ld4z(const float* __restrict__ line, int idx)
{
    if (idx >= 0 && idx < Z_) return *(const float4*)(line + idx);
    return make_float4(0.f, 0.f, 0.f, 0.f);
}

// ---------------- K1: products + z-filter, 8 outputs / thread ----------------
__global__ __launch_bounds__(256) void k_prod_zfilt(
    const float* __restrict__ I, const float* __restrict__ J,
    float* __restrict__ F, float* __restrict__ S)
{
    int t = blockIdx.x * 256 + threadIdx.x;      // 1,228,800 threads = 4800 * 256
    int chunk = t % CHUNKS;
    int line  = t / CHUNKS;                      // (b*X + x)*Y + y
    int z0 = chunk * RZ;
    const float* Ib = I + (size_t)line * Z_;
    const float* Jb = J + (size_t)line * Z_;

    float a[32], b[32];
    int zb = z0 - 12;
#pragma unroll
    for (int i = 0; i < 8; ++i) {
        float4 va = ld4z(Ib, zb + 4 * i);
        float4 vb = ld4z(Jb, zb + 4 * i);
        a[4 * i + 0] = va.x; a[4 * i + 1] = va.y; a[4 * i + 2] = va.z; a[4 * i + 3] = va.w;
        b[4 * i + 0] = vb.x; b[4 * i + 1] = vb.y; b[4 * i + 2] = vb.z; b[4 * i + 3] = vb.w;
    }

    float sI = 0.f, sJ = 0.f, sI2 = 0.f, sJ2 = 0.f, sIJ = 0.f;
#pragma unroll
    for (int k = 2; k <= 22; ++k) {
        float x = a[k], y = b[k];
        sI += x; sJ += y;
        sI2 = fmaf(x, x, sI2);
        sJ2 = fmaf(y, y, sJ2);
        sIJ = fmaf(x, y, sIJ);
    }
    float o0[RZ], o1[RZ], o2[RZ], o3[RZ], o4[RZ];
    o0[0] = sI; o1[0] = sJ; o2[0] = sI2; o3[0] = sJ2; o4[0] = sIJ;
#pragma unroll
    for (int r = 1; r < RZ; ++r) {
        float ae = a[r + 22], al = a[r + 1];
        float be = b[r + 22], bl = b[r + 1];
        sI += ae - al;
        sJ += be - bl;
        sI2 += fmaf(ae, ae, -(al * al));
        sJ2 += fmaf(be, be, -(bl * bl));
        sIJ += fmaf(ae, be, -(al * bl));
        o0[r] = sI; o1[r] = sJ; o2[r] = sI2; o3[r] = sJ2; o4[r] = sIJ;
    }

    size_t o = (size_t)line * Z_ + z0;           // 16B-aligned
    float* dst[5] = { F, F + NTOT, F + 2 * NTOT, F + 3 * NTOT, F + 4 * NTOT };
    float* arr[5] = { o0, o1, o2, o3, o4 };
#pragma unroll
    for (int c = 0; c < 5; ++c) {
        float* p = arr[c];
        *(float4*)(dst[c] + o)     = make_float4(p[0], p[1], p[2], p[3]);
        *(float4*)(dst[c] + o + 4) = make_float4(p[4], p[5], p[6], p[7]);
    }

    // mirror raw rows y in [53,73] u [117,137] into S[ch][sx][srow][z]
    int y  = line % Y_;
    int sx = line / Y_;
    if (y >= 53 && y <= 137) {
        int d = y - 53;
        int q = d >> 6;                          // 0 for [53,116], 1 for [117,...]
        int rem = d & 63;
        if (rem <= 20) {
            int srow = q * 21 + rem;
#pragma unroll
            for (int c = 0; c < 5; ++c) {
                float* p = arr[c];
                size_t so = (((size_t)c * SXN + sx) * SROWS + srow) * Z_ + z0;
                *(float4*)(S + so)     = make_float4(p[0], p[1], p[2], p[3]);
                *(float4*)(S + so + 4) = make_float4(p[4], p[5], p[6], p[7]);
            }
        }
    }
}

// ---------------- K2: y-filter, in place, register delay line ----------------
// Read row r: from S iff r is another segment's output AND in a boundary range.
__device__ __forceinline__ const float* ysrc(const float* __restrict__ Fb,
                                             const float* __restrict__ Sb,
                                             int r, int Y0, int YEND)
{
    if ((r < Y0 || r >= YEND) && r >= 53 && r <= 137) {
        int d = r - 53;
        int rem = d & 63;
        if (rem <= 20) return Sb + (size_t)((d >> 6) * 21 + rem) * Z_;
    }
    return Fb + (size_t)r * Z_;
}

template<int Y0>
__device__ __forceinline__ void yseg_run(float* __restrict__ Fb, const float* __restrict__ Sb)
{
    constexpr int YEND = Y0 + 64;
    float4 ring[11];                             // output delay line (registers)
    float W0 = 0.f, W1 = 0.f, W2 = 0.f, W3 = 0.f;

    // W = window sum at y = Y0-1: raw rows [Y0-11, Y0+9] clipped to >= 0
#pragma unroll
    for (int k = 0; k < WIN_; ++k) {
        int r = Y0 - 11 + k;                     // static per unrolled iter
        if (r >= 0) {
            float4 v = *(const float4*)ysrc(Fb, Sb, r, Y0, YEND);
            W0 += v.x; W1 += v.y; W2 += v.z; W3 += v.w;
        }
    }

    // 64 update steps + 11 flush steps = 75 iters; slot = (y-Y0) % 11 = i (static)
    for (int g = 0; g < 7; ++g) {
#pragma unroll
        for (int i = 0; i < 11; ++i) {
            int y = Y0 + g * 11 + i;
            if (y < YEND) {
                float4 e = make_float4(0.f, 0.f, 0.f, 0.f);
                float4 l = make_float4(0.f, 0.f, 0.f, 0.f);
                int ye = y + 10;
                if (ye < Y_) e = *(const float4*)ysrc(Fb, Sb, ye, Y0, YEND);
                int yl = y - 11;
                if (yl >= 0) l = *(const float4*)ysrc(Fb, Sb, yl, Y0, YEND);
                W0 += e.x - l.x; W1 += e.y - l.y; W2 += e.z - l.z; W3 += e.w - l.w;
                float4 old = ring[i];
                if (yl >= Y0)                    // write output row y-11 (raw was read above)
                    *(float4*)(Fb + (size_t)yl * Z_) = old;
                ring[i] = make_float4(W0, W1, W2, W3);
            } else if (y < YEND + 11) {          // flush last 11 outputs
                *(float4*)(Fb + (size_t)(y - 11) * Z_) = ring[i];
            }
        }
    }
}

// grid (250, 3): blockIdx.y = y-segment. Thread = (ch, sx, z4): 5*320*40 = 64000.
__global__ __launch_bounds__(256, 4) void k_yfilt(float* __restrict__ F,
                                                  const float* __restrict__ S)
{
    int c0 = blockIdx.x * 256 + threadIdx.x;     // [0, 64000)
    int z  = (c0 % 40) * 4;
    int sx = (c0 / 40) % SXN;
    int ch = c0 / (40 * SXN);
    float* Fb = F + (size_t)ch * NTOT + (size_t)sx * YZ + z;
    const float* Sb = S + ((size_t)ch * SXN + sx) * (SROWS * Z_) + z;
    switch (blockIdx.y) {
        case 0:  yseg_run<0>(Fb, Sb);   break;
        case 1:  yseg_run<64>(Fb, Sb);  break;
        default: yseg_run<128>(Fb, Sb); break;
    }
}

// ---------------- K3: x-filter + cc + reduction (4 x-segments) ----------------
__global__ __launch_bounds__(256) void k_xfilt_cc(const float* __restrict__ F,
                                                  double* __restrict__ acc)
{
    const float inv_n = 1.0f / 9261.0f;          // 21^3
    int t   = blockIdx.x * 256 + threadIdx.x;    // [0, 245760) = 960*256
    int col = t % (B_ * YZ);
    int seg = t / (B_ * YZ);
    int z   = col % Z_;
    int y   = (col / Z_) % Y_;
    int b   = col / YZ;
    const float* G = F + (size_t)b * X_ * YZ + (size_t)y * Z_ + z;

    float W0 = 0.f, W1 = 0.f, W2 = 0.f, W3 = 0.f, W4 = 0.f;
    int x0 = seg * XSEG;
    int pstart = x0 - HALF - 1; if (pstart < 0) pstart = 0;
    int pend = x0 + HALF - 1;
    for (int xx = pstart; xx <= pend; ++xx) {
        size_t o = (size_t)xx * YZ;
        W0 += G[o];            W1 += G[o + NTOT];     W2 += G[o + 2 * NTOT];
        W3 += G[o + 3 * NTOT]; W4 += G[o + 4 * NTOT];
    }

    float local = 0.f;
#pragma unroll 4
    for (int x = x0; x < x0 + XSEG; ++x) {
        float e0 = 0.f, e1 = 0.f, e2 = 0.f, e3 = 0.f, e4 = 0.f;
        int xe = x + HALF;
        if (xe < X_) {
            size_t o = (size_t)xe * YZ;
            e0 = G[o];            e1 = G[o + NTOT];     e2 = G[o + 2 * NTOT];
            e3 = G[o + 3 * NTOT]; e4 = G[o + 4 * NTOT];
        }
        int xl = x - HALF - 1;
        if (xl >= 0) {
            size_t o = (size_t)xl * YZ;
            e0 -= G[o];            e1 -= G[o + NTOT];     e2 -= G[o + 2 * NTOT];
            e3 -= G[o + 3 * NTOT]; e4 -= G[o + 4 * NTOT];
        }
        W0 += e0; W1 += e1; W2 += e2; W3 += e3; W4 += e4;

        float cross = fmaf(-(W0 * W1), inv_n, W4);
        float Iv    = fmaf(-(W0 * W0), inv_n, W2);
        float Jv    = fmaf(-(W1 * W1), inv_n, W3);
        float denom = fmaf(Iv, Jv, 1e-5f);
        local += (cross * cross) / denom;
    }

#pragma unroll
    for (int off = 32; off > 0; off >>= 1) local += __shfl_down(local, off);
    __shared__ float wsum[4];
    if ((threadIdx.x & 63) == 0) wsum[threadIdx.x >> 6] = local;
    __syncthreads();
    if (threadIdx.x == 0) {
        float sm = wsum[0] + wsum[1] + wsum[2] + wsum[3];
        atomicAdd(acc, (double)sm);
    }
}

// ---------------- K4: finalize ----------------
__global__ void k_final(const double* __restrict__ acc, float* __restrict__ out)
{
    out[0] = 1.0f - (float)(*acc / (double)(9830400.0));
}

extern "C" void kernel_launch(void* const* d_in, const int* in_sizes, int n_in,
                              void* d_out, int out_size, void* d_ws, size_t ws_size,
                              hipStream_t stream)
{
    const float* I = (const float*)d_in[0];
    const float* J = (const float*)d_in[1];
    float* out = (float*)d_out;

    char* ws = (char*)d_ws;
    double* acc = (double*)ws;                   // 8 B
    float* F = (float*)(ws + 256);               // 5 x 39.3 MB = 196.6 MB
    float* S = F + 5 * NTOT;                     // 5*320*42*160*4 = 43.0 MB

    hipMemsetAsync(acc, 0, sizeof(double), stream);

    k_prod_zfilt<<<dim3((int)(NTOT / RZ / 256)), 256, 0, stream>>>(I, J, F, S);

    k_yfilt<<<dim3(250, 3), 256, 0, stream>>>(F, S);

    k_xfilt_cc<<<dim3(960), 256, 0, stream>>>(F, acc);

    k_final<<<1, 1, 0, stream>>>(acc, out);
}

// Round 6
// 239.678 us; speedup vs baseline: 1.3542x; 1.3542x over previous
//
#include <hip/hip_runtime.h>

// NCC loss (win=21) on vol [B=2, C=1, X=160, Y=192, Z=160] fp32.
// Intermediates in fp16 (_Float16): F = 98.3 MB, S = 53.8 MB -> LLC-resident.
// K1: products + z-filter (register sliding window), fp32 in, fp16 out, mirrors
//     boundary rows to S. K2: y-filter in place, 6 y-segments of 32, register
//     delay line, half4 traffic. K3: x-filter + cc + reduce. K4: finalize.

typedef _Float16 h16;

#define B_   2
#define X_   160
#define Y_   192
#define Z_   160
#define WIN_ 21
#define HALF 10
#define YZ   (Y_ * Z_)                       // 30720
#define NTOT ((size_t)B_ * X_ * Y_ * Z_)     // 9830400
#define XSEG 40                              // K3: 4 x-segments
#define RZ   8                               // K1 outputs per thread
#define CHUNKS (Z_ / RZ)                     // 20
#define SXN  (B_ * X_)                       // 320
#define SROWS 105                            // 5 boundaries (32,64,96,128,160) x 21 rows [B-11,B+9]

union H8 { uint4 u; h16 h[8]; };
union H4 { uint2 u; h16 h[4]; };

__device__ __forceinline__ float4 ld_h4(const h16* __restrict__ p)
{
    H4 t; t.u = *(const uint2*)p;
    return make_float4((float)t.h[0], (float)t.h[1], (float)t.h[2], (float)t.h[3]);
}

// vector-or-zero fp32 load (float4 always fully in- or out-of-bounds; Z_ % 4 == 0)
__device__ __forceinline__ float4 ld4z(const float* __restrict__ line, int idx)
{
    if (idx >= 0 && idx < Z_) return *(const float4*)(line + idx);
    return make_float4(0.f, 0.f, 0.f, 0.f);
}

// ---------------- K1: products + z-filter, 8 outputs / thread ----------------
__global__ __launch_bounds__(256) void k_prod_zfilt(
    const float* __restrict__ I, const float* __restrict__ J,
    h16* __restrict__ F, h16* __restrict__ S)
{
    int t = blockIdx.x * 256 + threadIdx.x;      // 1,228,800 threads = 4800 * 256
    int chunk = t % CHUNKS;
    int line  = t / CHUNKS;                      // (b*X + x)*Y + y
    int z0 = chunk * RZ;
    const float* Ib = I + (size_t)line * Z_;
    const float* Jb = J + (size_t)line * Z_;

    float a[32], b[32];
    int zb = z0 - 12;
#pragma unroll
    for (int i = 0; i < 8; ++i) {
        float4 va = ld4z(Ib, zb + 4 * i);
        float4 vb = ld4z(Jb, zb + 4 * i);
        a[4 * i + 0] = va.x; a[4 * i + 1] = va.y; a[4 * i + 2] = va.z; a[4 * i + 3] = va.w;
        b[4 * i + 0] = vb.x; b[4 * i + 1] = vb.y; b[4 * i + 2] = vb.z; b[4 * i + 3] = vb.w;
    }

    float sI = 0.f, sJ = 0.f, sI2 = 0.f, sJ2 = 0.f, sIJ = 0.f;
#pragma unroll
    for (int k = 2; k <= 22; ++k) {
        float x = a[k], y = b[k];
        sI += x; sJ += y;
        sI2 = fmaf(x, x, sI2);
        sJ2 = fmaf(y, y, sJ2);
        sIJ = fmaf(x, y, sIJ);
    }
    float o0[RZ], o1[RZ], o2[RZ], o3[RZ], o4[RZ];
    o0[0] = sI; o1[0] = sJ; o2[0] = sI2; o3[0] = sJ2; o4[0] = sIJ;
#pragma unroll
    for (int r = 1; r < RZ; ++r) {
        float ae = a[r + 22], al = a[r + 1];
        float be = b[r + 22], bl = b[r + 1];
        sI += ae - al;
        sJ += be - bl;
        sI2 += fmaf(ae, ae, -(al * al));
        sJ2 += fmaf(be, be, -(bl * bl));
        sIJ += fmaf(ae, be, -(al * bl));
        o0[r] = sI; o1[r] = sJ; o2[r] = sI2; o3[r] = sJ2; o4[r] = sIJ;
    }

    // quantize once, store to F (and S mirror if boundary row)
    H8 w[5];
    float* arr[5] = { o0, o1, o2, o3, o4 };
#pragma unroll
    for (int c = 0; c < 5; ++c)
#pragma unroll
        for (int i = 0; i < 8; ++i) w[c].h[i] = (h16)arr[c][i];

    size_t o = (size_t)line * Z_ + z0;           // 16B-aligned in fp16
#pragma unroll
    for (int c = 0; c < 5; ++c)
        *(uint4*)(F + (size_t)c * NTOT + o) = w[c].u;

    int y  = line % Y_;
    int sx = line / Y_;
    if (y >= 21 && y <= 169) {
        int d = y - 21, rem = d & 31;
        if (rem <= 20) {
            int srow = (d >> 5) * 21 + rem;
#pragma unroll
            for (int c = 0; c < 5; ++c) {
                size_t so = (((size_t)c * SXN + sx) * SROWS + srow) * Z_ + z0;
                *(uint4*)(S + so) = w[c].u;
            }
        }
    }
}

// ---------------- K2: y-filter, in place, register delay line ----------------
// Row r for segment [Y0, YEND): other segments' rows come from the S mirror.
template<int Y0, int YEND>
__device__ __forceinline__ const h16* ysrc(const h16* __restrict__ Fb,
                                           const h16* __restrict__ Sb, int r)
{
    if ((Y0 > 0 && r < Y0) || r >= YEND) {       // always an S row by construction
        int d = r - 21;
        int srow = (d >> 5) * 21 + (d & 31);
        return Sb + (size_t)srow * Z_;
    }
    return Fb + (size_t)r * Z_;
}

template<int Y0>
__device__ __forceinline__ void yseg_run(h16* __restrict__ Fb, const h16* __restrict__ Sb)
{
    constexpr int YEND = Y0 + 32;
    uint2 ring[11];                              // fp16x4 output delay line
    float W0 = 0.f, W1 = 0.f, W2 = 0.f, W3 = 0.f;

    // W = window sum at y = Y0-1: raw rows [Y0-11, Y0+9] clipped to >= 0
#pragma unroll
    for (int k = 0; k < WIN_; ++k) {
        int r = Y0 - 11 + k;                     // static per unrolled iter
        if (r >= 0) {
            float4 v = ld_h4(ysrc<Y0, YEND>(Fb, Sb, r));
            W0 += v.x; W1 += v.y; W2 += v.z; W3 += v.w;
        }
    }

    // 32 update steps + 11 flush steps; slot = (y-Y0) % 11 = i (static)
#pragma unroll
    for (int g = 0; g < 4; ++g) {
#pragma unroll
        for (int i = 0; i < 11; ++i) {
            int y = Y0 + g * 11 + i;
            if (y < YEND) {
                float4 e = make_float4(0.f, 0.f, 0.f, 0.f);
                float4 l = make_float4(0.f, 0.f, 0.f, 0.f);
                int ye = y + 10;
                if (ye < Y_) e = ld_h4(ysrc<Y0, YEND>(Fb, Sb, ye));
                int yl = y - 11;
                if (yl >= 0) l = ld_h4(ysrc<Y0, YEND>(Fb, Sb, yl));
                W0 += e.x - l.x; W1 += e.y - l.y; W2 += e.z - l.z; W3 += e.w - l.w;
                if (yl >= Y0)                    // write output row y-11 (raw read above)
                    *(uint2*)(Fb + (size_t)yl * Z_) = ring[i];
                H4 t;
                t.h[0] = (h16)W0; t.h[1] = (h16)W1; t.h[2] = (h16)W2; t.h[3] = (h16)W3;
                ring[i] = t.u;
            } else if (y < YEND + 11) {          // flush last 11 outputs
                *(uint2*)(Fb + (size_t)(y - 11) * Z_) = ring[i];
            }
        }
    }
}

// grid (250, 6): blockIdx.y = y-segment (32 rows each). Thread = (ch, sx, z4).
__global__ __launch_bounds__(256) void k_yfilt(h16* __restrict__ F,
                                               const h16* __restrict__ S)
{
    int c0 = blockIdx.x * 256 + threadIdx.x;     // [0, 64000)
    int z  = (c0 % 40) * 4;
    int sx = (c0 / 40) % SXN;
    int ch = c0 / (40 * SXN);
    h16* Fb = F + (size_t)ch * NTOT + (size_t)sx * YZ + z;
    const h16* Sb = S + ((size_t)ch * SXN + sx) * ((size_t)SROWS * Z_) + z;
    switch (blockIdx.y) {
        case 0:  yseg_run<0>(Fb, Sb);   break;
        case 1:  yseg_run<32>(Fb, Sb);  break;
        case 2:  yseg_run<64>(Fb, Sb);  break;
        case 3:  yseg_run<96>(Fb, Sb);  break;
        case 4:  yseg_run<128>(Fb, Sb); break;
        default: yseg_run<160>(Fb, Sb); break;
    }
}

// ---------------- K3: x-filter + cc + reduction (4 x-segments) ----------------
__global__ __launch_bounds__(256) void k_xfilt_cc(const h16* __restrict__ F,
                                                  double* __restrict__ acc)
{
    const float inv_n = 1.0f / 9261.0f;          // 21^3
    int t   = blockIdx.x * 256 + threadIdx.x;    // [0, 245760) = 960*256
    int col = t % (B_ * YZ);
    int seg = t / (B_ * YZ);
    int z   = col % Z_;
    int y   = (col / Z_) % Y_;
    int b   = col / YZ;
    const h16* G = F + (size_t)b * X_ * YZ + (size_t)y * Z_ + z;

    float W0 = 0.f, W1 = 0.f, W2 = 0.f, W3 = 0.f, W4 = 0.f;
    int x0 = seg * XSEG;
    int pstart = x0 - HALF - 1; if (pstart < 0) pstart = 0;
    int pend = x0 + HALF - 1;
    for (int xx = pstart; xx <= pend; ++xx) {
        size_t o = (size_t)xx * YZ;
        W0 += (float)G[o];            W1 += (float)G[o + NTOT];
        W2 += (float)G[o + 2 * NTOT]; W3 += (float)G[o + 3 * NTOT];
        W4 += (float)G[o + 4 * NTOT];
    }

    float local = 0.f;
#pragma unroll 4
    for (int x = x0; x < x0 + XSEG; ++x) {
        float e0 = 0.f, e1 = 0.f, e2 = 0.f, e3 = 0.f, e4 = 0.f;
        int xe = x + HALF;
        if (xe < X_) {
            size_t o = (size_t)xe * YZ;
            e0 = (float)G[o];            e1 = (float)G[o + NTOT];
            e2 = (float)G[o + 2 * NTOT]; e3 = (float)G[o + 3 * NTOT];
            e4 = (float)G[o + 4 * NTOT];
        }
        int xl = x - HALF - 1;
        if (xl >= 0) {                           // leaving: exact same quantized value
            size_t o = (size_t)xl * YZ;
            e0 -= (float)G[o];            e1 -= (float)G[o + NTOT];
            e2 -= (float)G[o + 2 * NTOT]; e3 -= (float)G[o + 3 * NTOT];
            e4 -= (float)G[o + 4 * NTOT];
        }
        W0 += e0; W1 += e1; W2 += e2; W3 += e3; W4 += e4;

        float cross = fmaf(-(W0 * W1), inv_n, W4);
        float Iv    = fmaf(-(W0 * W0), inv_n, W2);
        float Jv    = fmaf(-(W1 * W1), inv_n, W3);
        float denom = fmaf(Iv, Jv, 1e-5f);
        local += (cross * cross) / denom;
    }

#pragma unroll
    for (int off = 32; off > 0; off >>= 1) local += __shfl_down(local, off);
    __shared__ float wsum[4];
    if ((threadIdx.x & 63) == 0) wsum[threadIdx.x >> 6] = local;
    __syncthreads();
    if (threadIdx.x == 0) {
        float sm = wsum[0] + wsum[1] + wsum[2] + wsum[3];
        atomicAdd(acc, (double)sm);
    }
}

// ---------------- K4: finalize ----------------
__global__ void k_final(const double* __restrict__ acc, float* __restrict__ out)
{
    out[0] = 1.0f - (float)(*acc / (double)(9830400.0));
}

extern "C" void kernel_launch(void* const* d_in, const int* in_sizes, int n_in,
                              void* d_out, int out_size, void* d_ws, size_t ws_size,
                              hipStream_t stream)
{
    const float* I = (const float*)d_in[0];
    const float* J = (const float*)d_in[1];
    float* out = (float*)d_out;

    char* ws = (char*)d_ws;
    double* acc = (double*)ws;                   // 8 B
    h16* F = (h16*)(ws + 256);                   // 5 x 19.66 MB = 98.3 MB
    h16* S = F + 5 * NTOT;                       // 5*320*105*160*2 = 53.8 MB

    hipMemsetAsync(acc, 0, sizeof(double), stream);

    k_prod_zfilt<<<dim3((int)(NTOT / RZ / 256)), 256, 0, stream>>>(I, J, F, S);

    k_yfilt<<<dim3(250, 6), 256, 0, stream>>>(F, S);

    k_xfilt_cc<<<dim3(960), 256, 0, stream>>>(F, acc);

    k_final<<<1, 1, 0, stream>>>(acc, out);
}

// Round 7
// 221.188 us; speedup vs baseline: 1.4674x; 1.0836x over previous
//
#include <hip/hip_runtime.h>

// NCC loss (win=21) on vol [B=2, C=1, X=160, Y=192, Z=160] fp32.
// Intermediates fp16. Ping-pong: K1 z-filter -> F; K2 y-filter F -> G with a
// 21-deep raw-value register ring (no in-place hazard, no side buffer);
// K3 x-filter + cc + reduce over G; K4 finalize.

typedef _Float16 h16;

#define B_   2
#define X_   160
#define Y_   192
#define Z_   160
#define WIN_ 21
#define HALF 10
#define YZ   (Y_ * Z_)                       // 30720
#define NTOT ((size_t)B_ * X_ * Y_ * Z_)     // 9830400
#define XSEG 40                              // K3: 4 x-segments
#define RZ   8                               // K1 outputs per thread
#define CHUNKS (Z_ / RZ)                     // 20
#define SXN  (B_ * X_)                       // 320
#define YSEG 48                              // K2: 4 y-segments of 48

union H8 { uint4 u; h16 h[8]; };
union H4 { uint2 u; h16 h[4]; };

// vector-or-zero fp32 load (float4 always fully in- or out-of-bounds; Z_ % 4 == 0)
__device__ __forceinline__ float4 ld4z(const float* __restrict__ line, int idx)
{
    if (idx >= 0 && idx < Z_) return *(const float4*)(line + idx);
    return make_float4(0.f, 0.f, 0.f, 0.f);
}

// ---------------- K1: products + z-filter, 8 outputs / thread ----------------
__global__ __launch_bounds__(256) void k_prod_zfilt(
    const float* __restrict__ I, const float* __restrict__ J,
    h16* __restrict__ F)
{
    int t = blockIdx.x * 256 + threadIdx.x;      // 1,228,800 threads = 4800 * 256
    int chunk = t % CHUNKS;
    int line  = t / CHUNKS;                      // (b*X + x)*Y + y
    int z0 = chunk * RZ;
    const float* Ib = I + (size_t)line * Z_;
    const float* Jb = J + (size_t)line * Z_;

    float a[32], b[32];
    int zb = z0 - 12;
#pragma unroll
    for (int i = 0; i < 8; ++i) {
        float4 va = ld4z(Ib, zb + 4 * i);
        float4 vb = ld4z(Jb, zb + 4 * i);
        a[4 * i + 0] = va.x; a[4 * i + 1] = va.y; a[4 * i + 2] = va.z; a[4 * i + 3] = va.w;
        b[4 * i + 0] = vb.x; b[4 * i + 1] = vb.y; b[4 * i + 2] = vb.z; b[4 * i + 3] = vb.w;
    }

    float sI = 0.f, sJ = 0.f, sI2 = 0.f, sJ2 = 0.f, sIJ = 0.f;
#pragma unroll
    for (int k = 2; k <= 22; ++k) {
        float x = a[k], y = b[k];
        sI += x; sJ += y;
        sI2 = fmaf(x, x, sI2);
        sJ2 = fmaf(y, y, sJ2);
        sIJ = fmaf(x, y, sIJ);
    }
    float o0[RZ], o1[RZ], o2[RZ], o3[RZ], o4[RZ];
    o0[0] = sI; o1[0] = sJ; o2[0] = sI2; o3[0] = sJ2; o4[0] = sIJ;
#pragma unroll
    for (int r = 1; r < RZ; ++r) {
        float ae = a[r + 22], al = a[r + 1];
        float be = b[r + 22], bl = b[r + 1];
        sI += ae - al;
        sJ += be - bl;
        sI2 += fmaf(ae, ae, -(al * al));
        sJ2 += fmaf(be, be, -(bl * bl));
        sIJ += fmaf(ae, be, -(al * bl));
        o0[r] = sI; o1[r] = sJ; o2[r] = sI2; o3[r] = sJ2; o4[r] = sIJ;
    }

    H8 w[5];
    float* arr[5] = { o0, o1, o2, o3, o4 };
#pragma unroll
    for (int c = 0; c < 5; ++c)
#pragma unroll
        for (int i = 0; i < 8; ++i) w[c].h[i] = (h16)arr[c][i];

    size_t o = (size_t)line * Z_ + z0;           // 16B-aligned in fp16
#pragma unroll
    for (int c = 0; c < 5; ++c)
        *(uint4*)(F + (size_t)c * NTOT + o) = w[c].u;
}

// ---------------- K2: y-filter F -> G, 21-deep raw register ring ----------------
// Ring invariant before step y: ring holds raw rows [y-11, y+9], slot (r-Y0+11)%21;
// W = their sum. Step y: leaving row y-11 is in slot (y-Y0)%21; entering row y+10
// replaces it. All slot indices static (full unroll, template Y0).
template<int Y0>
__device__ __forceinline__ void yseg_run(const h16* __restrict__ Fb, h16* __restrict__ Gb)
{
    uint2 ring[WIN_];
    float W0 = 0.f, W1 = 0.f, W2 = 0.f, W3 = 0.f;

#pragma unroll
    for (int k = 0; k < WIN_; ++k) {             // preload raw rows [Y0-11, Y0+9]
        int r = Y0 - 11 + k;                     // static; r <= 153 < Y_ always
        uint2 v = make_uint2(0u, 0u);
        if (r >= 0) v = *(const uint2*)(Fb + (size_t)r * Z_);
        ring[k] = v;
        H4 t; t.u = v;
        W0 += (float)t.h[0]; W1 += (float)t.h[1];
        W2 += (float)t.h[2]; W3 += (float)t.h[3];
    }

#pragma unroll
    for (int g = 0; g < 3; ++g) {
#pragma unroll
        for (int i = 0; i < WIN_; ++i) {
            int step = g * WIN_ + i;             // static
            if (step < YSEG) {
                int y = Y0 + step;
                int ye = y + HALF;
                uint2 e = make_uint2(0u, 0u);
                if (ye < Y_) e = *(const uint2*)(Fb + (size_t)ye * Z_);
                H4 te; te.u = e;
                H4 tl; tl.u = ring[i];           // leaving raw row y-11
                W0 += (float)te.h[0] - (float)tl.h[0];
                W1 += (float)te.h[1] - (float)tl.h[1];
                W2 += (float)te.h[2] - (float)tl.h[2];
                W3 += (float)te.h[3] - (float)tl.h[3];
                ring[i] = e;
                H4 o;
                o.h[0] = (h16)W0; o.h[1] = (h16)W1;
                o.h[2] = (h16)W2; o.h[3] = (h16)W3;
                *(uint2*)(Gb + (size_t)y * Z_) = o.u;
            }
        }
    }
}

// 1000 blocks x 256: thread = (ch, seg, sx, z4). seg/ch uniform per block.
__global__ __launch_bounds__(256) void k_yfilt(const h16* __restrict__ F,
                                               h16* __restrict__ G)
{
    int c0 = blockIdx.x * 256 + threadIdx.x;     // [0, 256000)
    int z  = (c0 % 40) * 4;
    int sx = (c0 / 40) % SXN;
    int rest = c0 / (40 * SXN);                  // [0, 20) = ch*4 + seg
    int ch = rest >> 2;
    int seg = rest & 3;
    size_t off = (size_t)ch * NTOT + (size_t)sx * YZ + z;
    const h16* Fb = F + off;
    h16* Gb = G + off;
    switch (seg) {
        case 0:  yseg_run<0>(Fb, Gb);   break;
        case 1:  yseg_run<48>(Fb, Gb);  break;
        case 2:  yseg_run<96>(Fb, Gb);  break;
        default: yseg_run<144>(Fb, Gb); break;
    }
}

// ---------------- K3: x-filter + cc + reduction (4 x-segments) ----------------
__global__ __launch_bounds__(256) void k_xfilt_cc(const h16* __restrict__ G,
                                                  double* __restrict__ acc)
{
    const float inv_n = 1.0f / 9261.0f;          // 21^3
    int t   = blockIdx.x * 256 + threadIdx.x;    // [0, 245760) = 960*256
    int col = t % (B_ * YZ);
    int seg = t / (B_ * YZ);
    int z   = col % Z_;
    int y   = (col / Z_) % Y_;
    int b   = col / YZ;
    const h16* Gp = G + (size_t)b * X_ * YZ + (size_t)y * Z_ + z;

    float W0 = 0.f, W1 = 0.f, W2 = 0.f, W3 = 0.f, W4 = 0.f;
    int x0 = seg * XSEG;
    int pstart = x0 - HALF - 1; if (pstart < 0) pstart = 0;
    int pend = x0 + HALF - 1;
    for (int xx = pstart; xx <= pend; ++xx) {
        size_t o = (size_t)xx * YZ;
        W0 += (float)Gp[o];            W1 += (float)Gp[o + NTOT];
        W2 += (float)Gp[o + 2 * NTOT]; W3 += (float)Gp[o + 3 * NTOT];
        W4 += (float)Gp[o + 4 * NTOT];
    }

    float local = 0.f;
#pragma unroll 4
    for (int x = x0; x < x0 + XSEG; ++x) {
        float e0 = 0.f, e1 = 0.f, e2 = 0.f, e3 = 0.f, e4 = 0.f;
        int xe = x + HALF;
        if (xe < X_) {
            size_t o = (size_t)xe * YZ;
            e0 = (float)Gp[o];            e1 = (float)Gp[o + NTOT];
            e2 = (float)Gp[o + 2 * NTOT]; e3 = (float)Gp[o + 3 * NTOT];
            e4 = (float)Gp[o + 4 * NTOT];
        }
        int xl = x - HALF - 1;
        if (xl >= 0) {                           // leaving: same quantized value, exact
            size_t o = (size_t)xl * YZ;
            e0 -= (float)Gp[o];            e1 -= (float)Gp[o + NTOT];
            e2 -= (float)Gp[o + 2 * NTOT]; e3 -= (float)Gp[o + 3 * NTOT];
            e4 -= (float)Gp[o + 4 * NTOT];
        }
        W0 += e0; W1 += e1; W2 += e2; W3 += e3; W4 += e4;

        float cross = fmaf(-(W0 * W1), inv_n, W4);
        float Iv    = fmaf(-(W0 * W0), inv_n, W2);
        float Jv    = fmaf(-(W1 * W1), inv_n, W3);
        float denom = fmaf(Iv, Jv, 1e-5f);
        local += (cross * cross) / denom;
    }

#pragma unroll
    for (int off = 32; off > 0; off >>= 1) local += __shfl_down(local, off);
    __shared__ float wsum[4];
    if ((threadIdx.x & 63) == 0) wsum[threadIdx.x >> 6] = local;
    __syncthreads();
    if (threadIdx.x == 0) {
        float sm = wsum[0] + wsum[1] + wsum[2] + wsum[3];
        atomicAdd(acc, (double)sm);
    }
}

// ---------------- K4: finalize ----------------
__global__ void k_final(const double* __restrict__ acc, float* __restrict__ out)
{
    out[0] = 1.0f - (float)(*acc / (double)(9830400.0));
}

extern "C" void kernel_launch(void* const* d_in, const int* in_sizes, int n_in,
                              void* d_out, int out_size, void* d_ws, size_t ws_size,
                              hipStream_t stream)
{
    const float* I = (const float*)d_in[0];
    const float* J = (const float*)d_in[1];
    float* out = (float*)d_out;

    char* ws = (char*)d_ws;
    double* acc = (double*)ws;                   // 8 B
    h16* F = (h16*)(ws + 256);                   // 5 x 19.66 MB = 98.3 MB
    h16* G = F + 5 * NTOT;                       // 98.3 MB ping-pong

    hipMemsetAsync(acc, 0, sizeof(double), stream);

    k_prod_zfilt<<<dim3((int)(NTOT / RZ / 256)), 256, 0, stream>>>(I, J, F);

    k_yfilt<<<dim3(1000), 256, 0, stream>>>(F, G);

    k_xfilt_cc<<<dim3(960), 256, 0, stream>>>(G, acc);

    k_final<<<1, 1, 0, stream>>>(acc, out);
}